// Round 4
// baseline (78.505 us; speedup 1.0000x reference)
//
#include <hip/hip_runtime.h>
#include <hip/hip_bf16.h>

// LinearAttention_41798621725051 on MI355X.
// Identity: (qk * v_h) / qk == v_h elementwise (qk strictly positive, finite),
// so reference == cumsum_b( v @ Wv^T ): one bf16 MFMA GEMM (M=16384, N=K=1024),
// batch-cumsum free in the epilogue (C/D frag rows = 4 batch entries of one s).
//
// R4: TLP round. BM=128/BN=256/BK=32, 8 waves (64x64 wave tile, acc=64 regs),
// 48 KB LDS dbuf, <=128 regs/wave (launch_bounds 512,4) -> 2 blocks/CU.
// One barrier per K-step; B-stage issued early (T14), A-stage transient.

typedef short s16x8 __attribute__((ext_vector_type(8)));
typedef float f32x4 __attribute__((ext_vector_type(4)));

constexpr int M_ = 16384, N_ = 1024, K_ = 1024;
constexpr int BM = 128, BN = 256, BK = 32;
constexpr int KSTEPS = K_ / BK;   // 32

static __device__ __forceinline__ unsigned cvtpk(float lo, float hi) {
  unsigned r;
  asm("v_cvt_pk_bf16_f32 %0, %1, %2" : "=v"(r) : "v"(lo), "v"(hi));
  return r;
}

// row-major [rows][32 bf16 = 4 x 16B chunks]; chunk' = chunk ^ ((row>>1 ^ row>>3)&3)
// (bit3 folded in so rows 8/16/24 apart don't alias the same bank quad)
static __device__ __forceinline__ int swz(int row, int chunk) {
  return row * 64 + (((chunk ^ ((row >> 1) ^ (row >> 3))) & 3) << 4);
}

__global__ __launch_bounds__(512, 4) void la_gemm_cumsum(
    const float* __restrict__ Vp,   // (M, K) f32
    const float* __restrict__ Wp,   // (N, K) f32 (Wv, B^T layout)
    float* __restrict__ out)        // (M, N) f32
{
  __shared__ __align__(16) char lds[2][24576];   // per buf: A 8KB | B 16KB

  const int tid  = threadIdx.x;
  const int lane = tid & 63;
  const int wave = tid >> 6;
  const int wr = wave >> 2;         // 0..1 (64 rows each)
  const int wc = wave & 3;          // 0..3 (64 cols each)

  // XCD-affine: 4 nt-blocks of one mt share an XCD's L2 (A-strip L2 reuse).
  const int gid = blockIdx.x;       // 0..511, gid%8 = XCD
  const int xcd = gid & 7;
  const int q   = gid >> 3;         // 0..63
  const int mt  = xcd * 16 + (q >> 2);  // 0..127
  const int nt  = q & 3;                // 0..3

  // ---- staging addressing (iteration-invariant)
  const int arow = tid >> 2, ac = tid & 3;       // A: 128 rows x 4 chunks(8 f32)
  const float* sAp = Vp + (size_t)(mt * BM + arow) * K_ + ac * 8;
  const int awb = swz(arow, ac);
  const int brow = tid >> 1, bh = tid & 1;       // B: 256 rows x 2 halves(16 f32)
  const float* sBp = Wp + (size_t)(nt * BN + brow) * K_ + bh * 16;
  const int bwb0 = swz(brow, 2 * bh);
  const int bwb1 = swz(brow, 2 * bh + 1);

  f32x4 acc[4][4] = {};

  auto loadB = [&](int kt, float4& b0, float4& b1, float4& b2, float4& b3) {
    const float* p = sBp + kt * BK;
    b0 = *(const float4*)p;       b1 = *(const float4*)(p + 4);
    b2 = *(const float4*)(p + 8); b3 = *(const float4*)(p + 12);
  };
  auto writeB = [&](int buf, float4 b0, float4 b1, float4 b2, float4 b3) {
    char* B = lds[buf] + 8192;
    uint4 w0, w1;
    w0.x = cvtpk(b0.x, b0.y); w0.y = cvtpk(b0.z, b0.w);
    w0.z = cvtpk(b1.x, b1.y); w0.w = cvtpk(b1.z, b1.w);
    w1.x = cvtpk(b2.x, b2.y); w1.y = cvtpk(b2.z, b2.w);
    w1.z = cvtpk(b3.x, b3.y); w1.w = cvtpk(b3.z, b3.w);
    *(uint4*)(B + bwb0) = w0;
    *(uint4*)(B + bwb1) = w1;
  };
  auto stageA = [&](int kt, int buf) {            // transient: load+cvt+write
    const float* p = sAp + kt * BK;
    float4 a0 = *(const float4*)p, a1 = *(const float4*)(p + 4);
    uint4 w;
    w.x = cvtpk(a0.x, a0.y); w.y = cvtpk(a0.z, a0.w);
    w.z = cvtpk(a1.x, a1.y); w.w = cvtpk(a1.z, a1.w);
    *(uint4*)(lds[buf] + awb) = w;
  };

  auto compute = [&](int buf) {   // 8 ds_read_b128 + 16 MFMA per wave
    const char* A = lds[buf];
    const char* B = lds[buf] + 8192;
    s16x8 af[4], bf[4];
#pragma unroll
    for (int n = 0; n < 4; ++n) {
      const int row = wc * 64 + n * 16 + (lane & 15);
      bf[n] = *(const s16x8*)(B + swz(row, lane >> 4));
    }
#pragma unroll
    for (int m = 0; m < 4; ++m) {
      const int row = wr * 64 + m * 16 + (lane & 15);
      af[m] = *(const s16x8*)(A + swz(row, lane >> 4));
    }
    __builtin_amdgcn_s_setprio(1);
#pragma unroll
    for (int m = 0; m < 4; ++m)
#pragma unroll
      for (int n = 0; n < 4; ++n)
        acc[m][n] = __builtin_amdgcn_mfma_f32_16x16x32_bf16(af[m], bf[n], acc[m][n], 0, 0, 0);
    __builtin_amdgcn_s_setprio(0);
  };

  // ---- prologue: stage step 0 into buf 0
  {
    float4 b0, b1, b2, b3;
    loadB(0, b0, b1, b2, b3);
    writeB(0, b0, b1, b2, b3);
    stageA(0, 0);
  }
  __syncthreads();

  // ---- main loop: ONE barrier per K-step.
  // B loads for kt+1 in flight across compute(kt) (T14); A staged transiently
  // after compute (stall covered by the co-resident block / other waves).
  for (int kt = 0; kt < KSTEPS; ++kt) {
    const int cur = kt & 1;
    float4 b0, b1, b2, b3;
    const bool pf = (kt + 1 < KSTEPS);
    if (pf) loadB(kt + 1, b0, b1, b2, b3);
    compute(cur);
    if (pf) {
      writeB(cur ^ 1, b0, b1, b2, b3);
      stageA(kt + 1, cur ^ 1);
    }
    __syncthreads();
  }

  // ---- epilogue: batch-cumsum = prefix over f32x4 (rows s*4 + 0..3)
#pragma unroll
  for (int m = 0; m < 4; ++m) {
    const int row0 = mt * BM + wr * 64 + m * 16 + ((lane >> 4) << 2);
#pragma unroll
    for (int n = 0; n < 4; ++n) {
      f32x4 a = acc[m][n];
      a.y += a.x;  a.z += a.y;  a.w += a.z;
      const int col = nt * BN + wc * 64 + n * 16 + (lane & 15);
      out[(size_t)(row0 + 0) * N_ + col] = a.x;
      out[(size_t)(row0 + 1) * N_ + col] = a.y;
      out[(size_t)(row0 + 2) * N_ + col] = a.z;
      out[(size_t)(row0 + 3) * N_ + col] = a.w;
    }
  }
}

extern "C" void kernel_launch(void* const* d_in, const int* in_sizes, int n_in,
                              void* d_out, int out_size, void* d_ws, size_t ws_size,
                              hipStream_t stream) {
  // setup_inputs order: q, k, v, Wq, Wk, Wv — only v and Wv matter.
  const float* v  = (const float*)d_in[2];
  const float* Wv = (const float*)d_in[5];
  float* out = (float*)d_out;
  (void)d_ws; (void)ws_size; (void)in_sizes; (void)n_in; (void)out_size;

  la_gemm_cumsum<<<dim3((M_ / BM) * (N_ / BN)), dim3(512), 0, stream>>>(v, Wv, out);
}

// Round 5
// 57.933 us; speedup vs baseline: 1.3551x; 1.3551x over previous
//
#include <hip/hip_runtime.h>
#include <hip/hip_bf16.h>

// LinearAttention_41798621725051 on MI355X.
// Identity: (qk * v_h) / qk == v_h elementwise (qk strictly positive, finite),
// so reference == cumsum_b( v @ Wv^T ): one bf16 MFMA GEMM (M=16384, N=K=1024),
// batch-cumsum free in the epilogue (C/D frag rows = 4 batch entries of one s).
//
// R5: m201 8-phase schedule (T3+T4) on R3's geometry: 256x256, BK=64, 8 waves
// (2Mx4N), 128 KiB LDS dbuf, grid=256 XCD-affine. 4 phases per K-tile, each =
// {ds_read quadrant | stage group ; s_barrier ; lgkmcnt(0)+sched_barrier ;
//  setprio(1) 16xMFMA setprio(0) ; s_barrier}. Loads for kt+1 issued P0/P1,
// cvt+ds_write in P2/P3 (counted vmcnt by register deps, never drain-0).

typedef short s16x8 __attribute__((ext_vector_type(8)));
typedef float f32x4 __attribute__((ext_vector_type(4)));

constexpr int M_ = 16384, N_ = 1024, K_ = 1024;
constexpr int BM = 256, BN = 256, BK = 64;
constexpr int KT = K_ / BK;            // 16
constexpr int LDS_BUF = 65536;         // 32KB A | 32KB B
constexpr size_t LDS_TOTAL = 131072;

static __device__ __forceinline__ unsigned cvtpk(float lo, float hi) {
  unsigned r;
  asm("v_cvt_pk_bf16_f32 %0, %1, %2" : "=v"(r) : "v"(lo), "v"(hi));
  return r;
}

__global__ __launch_bounds__(512, 2) void la_gemm_cumsum(
    const float* __restrict__ Vp,   // (M, K) f32
    const float* __restrict__ Wp,   // (N, K) f32 (Wv, B^T layout)
    float* __restrict__ out)        // (M, N) f32
{
  extern __shared__ char lds[];     // [2][A 32KB | B 32KB]

  const int tid  = threadIdx.x;
  const int lane = tid & 63;
  const int wave = tid >> 6;
  const int wr = wave >> 2;         // 0..1 (128 rows)
  const int wc = wave & 3;          // 0..3 (64 cols)

  // XCD-affine: 4 nt-blocks of one mt share an XCD's L2 (A-strip reuse).
  const int gid = blockIdx.x;
  const int xcd = gid & 7;
  const int q   = gid >> 3;
  const int mt  = xcd * 8 + (q >> 2);
  const int nt  = q & 3;

  // staging addressing (iteration-invariant); swizzle chunk' = chunk ^ (row&7)
  const int srow   = tid >> 3;      // 0..63
  const int schunk = tid & 7;       // 8-float chunk in BK=64
  const float* sAp = Vp + (size_t)(mt * 256 + srow) * K_ + schunk * 8;
  const float* sBp = Wp + (size_t)(nt * 256 + srow) * K_ + schunk * 8;
  const int wbyte = srow * 128 + ((schunk ^ (srow & 7)) << 4);

  // fragment read bases (row&7 == lane&7); kk=1 is base ^ 64 (chunk ^= 4)
  const int basa0 = (wr * 128 + (lane & 15)) * 128 + (((lane >> 4) ^ (lane & 7)) << 4);
  const int basb0 = (wc * 64 + (lane & 15)) * 128 + (((lane >> 4) ^ (lane & 7)) << 4);

  f32x4 acc[8][4] = {};
  float4 sa[8], sb[8];              // stage regs, all indices compile-time

#define LOADGRP(g, kt1) do {                                                  \
    const float* pa_ = sAp + (kt1) * 64 + (g) * (64 * K_);                    \
    const float* pb_ = sBp + (kt1) * 64 + (g) * (64 * K_);                    \
    sa[2*(g)]   = *(const float4*)pa_;  sa[2*(g)+1] = *(const float4*)(pa_+4);\
    sb[2*(g)]   = *(const float4*)pb_;  sb[2*(g)+1] = *(const float4*)(pb_+4);\
  } while (0)

#define WRITEGRP(g, Aw, Bw) do {                                              \
    uint4 wa_, wb_;                                                           \
    wa_.x = cvtpk(sa[2*(g)].x,   sa[2*(g)].y);                                \
    wa_.y = cvtpk(sa[2*(g)].z,   sa[2*(g)].w);                                \
    wa_.z = cvtpk(sa[2*(g)+1].x, sa[2*(g)+1].y);                              \
    wa_.w = cvtpk(sa[2*(g)+1].z, sa[2*(g)+1].w);                              \
    wb_.x = cvtpk(sb[2*(g)].x,   sb[2*(g)].y);                                \
    wb_.y = cvtpk(sb[2*(g)].z,   sb[2*(g)].w);                                \
    wb_.z = cvtpk(sb[2*(g)+1].x, sb[2*(g)+1].y);                              \
    wb_.w = cvtpk(sb[2*(g)+1].z, sb[2*(g)+1].w);                              \
    *(uint4*)((Aw) + wbyte + (g) * 8192) = wa_;                               \
    *(uint4*)((Bw) + wbyte + (g) * 8192) = wb_;                               \
  } while (0)

#define DSREAD_A(Abuf, kk, mh, af) do {                                       \
    const int ba_ = basa0 ^ ((kk) ? 64 : 0);                                  \
    _Pragma("unroll")                                                         \
    for (int m_ = 0; m_ < 4; ++m_)                                            \
      af[m_] = *(const s16x8*)((Abuf) + ba_ + ((mh)*4 + m_) * 2048);          \
  } while (0)

#define DSREAD_B(Bbuf, kk, bf) do {                                           \
    const int bb_ = basb0 ^ ((kk) ? 64 : 0);                                  \
    _Pragma("unroll")                                                         \
    for (int n_ = 0; n_ < 4; ++n_)                                            \
      bf[n_] = *(const s16x8*)((Bbuf) + bb_ + n_ * 2048);                     \
  } while (0)

#define MFMA16(mh, af, bf) do {                                               \
    __builtin_amdgcn_s_setprio(1);                                            \
    _Pragma("unroll")                                                         \
    for (int m_ = 0; m_ < 4; ++m_)                                            \
      _Pragma("unroll")                                                       \
      for (int n_ = 0; n_ < 4; ++n_)                                          \
        acc[(mh)*4 + m_][n_] = __builtin_amdgcn_mfma_f32_16x16x32_bf16(       \
            af[m_], bf[n_], acc[(mh)*4 + m_][n_], 0, 0, 0);                   \
    __builtin_amdgcn_s_setprio(0);                                            \
  } while (0)

#define PHASE_GATE()                                                          \
    __builtin_amdgcn_s_barrier();                                             \
    asm volatile("s_waitcnt lgkmcnt(0)" ::: "memory");                        \
    __builtin_amdgcn_sched_barrier(0);

  // ---- prologue: tile 0 into buf0
  LOADGRP(0, 0); LOADGRP(1, 0); LOADGRP(2, 0); LOADGRP(3, 0);
  {
    char* Aw = lds; char* Bw = lds + 32768;
    WRITEGRP(0, Aw, Bw); WRITEGRP(1, Aw, Bw);
    WRITEGRP(2, Aw, Bw); WRITEGRP(3, Aw, Bw);
  }
  __syncthreads();

  // ---- main loop: 4 phases per K-tile, 2 s_barriers per phase, no drain-0.
  for (int kt = 0; kt < KT; ++kt) {
    const int cur = kt & 1;
    const char* A = lds + cur * LDS_BUF;
    const char* B = A + 32768;
    char* Aw = lds + (cur ^ 1) * LDS_BUF;
    char* Bw = Aw + 32768;
    const bool pf = (kt + 1 < KT);

    s16x8 af[4], bf0[4], bf1[4];

    // P0: quadrant (kk=0, mh=0); issue load groups 0,1 for kt+1
    DSREAD_B(B, 0, bf0);
    DSREAD_A(A, 0, 0, af);
    if (pf) { LOADGRP(0, kt + 1); LOADGRP(1, kt + 1); }
    PHASE_GATE();
    MFMA16(0, af, bf0);
    __builtin_amdgcn_s_barrier();

    // P1: (kk=0, mh=1); issue load groups 2,3
    DSREAD_A(A, 0, 1, af);
    if (pf) { LOADGRP(2, kt + 1); LOADGRP(3, kt + 1); }
    PHASE_GATE();
    MFMA16(1, af, bf0);
    __builtin_amdgcn_s_barrier();

    // P2: (kk=1, mh=0); commit stage groups 0,1 (vmcnt counted via reg deps)
    DSREAD_B(B, 1, bf1);
    DSREAD_A(A, 1, 0, af);
    if (pf) { WRITEGRP(0, Aw, Bw); WRITEGRP(1, Aw, Bw); }
    PHASE_GATE();
    MFMA16(0, af, bf1);
    __builtin_amdgcn_s_barrier();

    // P3: (kk=1, mh=1); commit stage groups 2,3. Each wave's writes drain at
    // the lgkmcnt(0) below, BEFORE the closing barrier -> next tile's reads
    // of buf^1 are safe without __syncthreads.
    DSREAD_A(A, 1, 1, af);
    if (pf) { WRITEGRP(2, Aw, Bw); WRITEGRP(3, Aw, Bw); }
    PHASE_GATE();
    MFMA16(1, af, bf1);
    __builtin_amdgcn_s_barrier();
  }

  // ---- epilogue: batch-cumsum = prefix over f32x4 (rows s*4 + 0..3)
#pragma unroll
  for (int m = 0; m < 8; ++m) {
    const int row0 = mt * 256 + wr * 128 + m * 16 + ((lane >> 4) << 2);
#pragma unroll
    for (int n = 0; n < 4; ++n) {
      f32x4 a = acc[m][n];
      a.y += a.x;  a.z += a.y;  a.w += a.z;
      const int col = nt * 256 + wc * 64 + n * 16 + (lane & 15);
      out[(size_t)(row0 + 0) * N_ + col] = a.x;
      out[(size_t)(row0 + 1) * N_ + col] = a.y;
      out[(size_t)(row0 + 2) * N_ + col] = a.z;
      out[(size_t)(row0 + 3) * N_ + col] = a.w;
    }
  }

#undef LOADGRP
#undef WRITEGRP
#undef DSREAD_A
#undef DSREAD_B
#undef MFMA16
#undef PHASE_GATE
}

extern "C" void kernel_launch(void* const* d_in, const int* in_sizes, int n_in,
                              void* d_out, int out_size, void* d_ws, size_t ws_size,
                              hipStream_t stream) {
  // setup_inputs order: q, k, v, Wq, Wk, Wv — only v and Wv matter.
  const float* v  = (const float*)d_in[2];
  const float* Wv = (const float*)d_in[5];
  float* out = (float*)d_out;
  (void)d_ws; (void)ws_size; (void)in_sizes; (void)n_in; (void)out_size;

  hipFuncSetAttribute((const void*)la_gemm_cumsum,
                      hipFuncAttributeMaxDynamicSharedMemorySize, (int)LDS_TOTAL);

  la_gemm_cumsum<<<dim3(256), dim3(512), LDS_TOTAL, stream>>>(v, Wv, out);
}